// Round 7
// baseline (1914.651 us; speedup 1.0000x reference)
//
#include <hip/hip_runtime.h>
#include <hip/hip_bf16.h>
#include <math.h>

#define BB 2
#define SS 4096
#define HIDK 512
#define HH 8
#define DD 64
#define NHH 4
#define NCC 256      // chunks per (b,h) = NH*S/CHUNK
#define RANKS 16384  // NH*S

typedef unsigned int u32;
typedef unsigned short u16;
typedef unsigned char u8;

__device__ __forceinline__ float bflo(u32 u){ return __uint_as_float(u << 16); }
__device__ __forceinline__ float bfhi(u32 u){ return __uint_as_float(u & 0xffff0000u); }

// ---------------------------------------------------------------------------
// Kernel 0: input dtype detection (bf16 vs fp32 bit patterns in w_qk).
// ---------------------------------------------------------------------------
__global__ __launch_bounds__(256) void k_detect(const u32* __restrict__ w, int* __restrict__ flag)
{
  int i = blockIdx.x * 256 + threadIdx.x;   // grid 512 -> 131072 u32
  float lo = bflo(w[i]);
  bool bad = !(fabsf(lo) <= 1024.0f);       // true also for NaN
  if (__any(bad)) {
    if ((threadIdx.x & 63) == 0) atomicOr(flag, 1);
  }
}

// ---------------------------------------------------------------------------
// Kernel 1: projections, fp32 accumulation.
// which=0: q=dec@wqk -> qb   (raw; hash + attention)
// which=1: k=hid@wqk -> kraw (raw; hash + attention, normalized in-LDS later)
// which=2: v=hid@wv  -> vb   (fp32)
// All outputs [B,H,S,D] fp32.
// ---------------------------------------------------------------------------
__global__ __launch_bounds__(256) void k_proj(
    const u32* __restrict__ dec, const u32* __restrict__ hid,
    const u32* __restrict__ wqk, const u32* __restrict__ wv,
    const int* __restrict__ flag,
    float* __restrict__ qb, float* __restrict__ kraw, float* __restrict__ vb)
{
  const int which = blockIdx.z;
  const u32* A = (which == 0) ? dec : hid;
  const u32* W = (which == 2) ? wv : wqk;
  const int m0 = blockIdx.x * 64;
  const int h  = blockIdx.y;
  const int t  = threadIdx.x;
  const int ty = t >> 4, tx = t & 15;
  const int is32 = flag[0];

  __shared__ float AsT[32][65];     // [kk][row i]
  __shared__ float Wst[32][4][16];  // [kk][c&3][c>>2] = W[kk][col c]

  float acc[4][4];
  #pragma unroll
  for (int r = 0; r < 4; ++r)
    #pragma unroll
    for (int c = 0; c < 4; ++c) acc[r][c] = 0.0f;

  for (int k0 = 0; k0 < HIDK; k0 += 32) {
    if (is32) {
      const float* Af = (const float*)A;
      const float* Wf = (const float*)W;
      #pragma unroll
      for (int it = 0; it < 8; ++it) {
        int idx = t + it * 256;          // 2048: 64 rows x 32 k
        int i = idx >> 5, kk = idx & 31;
        AsT[kk][i] = Af[(size_t)(m0 + i) * HIDK + k0 + kk];
      }
      #pragma unroll
      for (int it = 0; it < 8; ++it) {
        int idx = t + it * 256;          // 2048: 32 rows x 64 cols
        int kk = idx >> 6, c = idx & 63;
        Wst[kk][c & 3][c >> 2] = Wf[(size_t)(k0 + kk) * HIDK + h * 64 + c];
      }
    } else {
      #pragma unroll
      for (int it = 0; it < 4; ++it) {
        int idx = t + it * 256;          // 1024: A tile 64 rows x 16 u32
        int i = idx >> 4, kp = idx & 15;
        u32 uv = A[(size_t)(m0 + i) * (HIDK / 2) + (k0 >> 1) + kp];
        AsT[2 * kp][i]     = bflo(uv);
        AsT[2 * kp + 1][i] = bfhi(uv);
      }
      #pragma unroll
      for (int it = 0; it < 4; ++it) {
        int idx = t + it * 256;          // 1024: W tile 32 rows x 32 u32
        int kk = idx >> 5, cp = idx & 31;
        u32 uv = W[(size_t)(k0 + kk) * (HIDK / 2) + h * 32 + cp];
        int c0 = 2 * cp, c1 = 2 * cp + 1;
        Wst[kk][c0 & 3][c0 >> 2] = bflo(uv);
        Wst[kk][c1 & 3][c1 >> 2] = bfhi(uv);
      }
    }
    __syncthreads();
    for (int kk = 0; kk < 32; ++kk) {
      float a0 = AsT[kk][ty * 4 + 0];
      float a1 = AsT[kk][ty * 4 + 1];
      float a2 = AsT[kk][ty * 4 + 2];
      float a3 = AsT[kk][ty * 4 + 3];
      float w0 = Wst[kk][0][tx];
      float w1 = Wst[kk][1][tx];
      float w2 = Wst[kk][2][tx];
      float w3 = Wst[kk][3][tx];
      acc[0][0] += a0 * w0; acc[0][1] += a0 * w1; acc[0][2] += a0 * w2; acc[0][3] += a0 * w3;
      acc[1][0] += a1 * w0; acc[1][1] += a1 * w1; acc[1][2] += a1 * w2; acc[1][3] += a1 * w3;
      acc[2][0] += a2 * w0; acc[2][1] += a2 * w1; acc[2][2] += a2 * w2; acc[2][3] += a2 * w3;
      acc[3][0] += a3 * w0; acc[3][1] += a3 * w1; acc[3][2] += a3 * w2; acc[3][3] += a3 * w3;
    }
    __syncthreads();
  }

  float* outp = (which == 0) ? qb : ((which == 1) ? kraw : vb);
  #pragma unroll
  for (int r = 0; r < 4; ++r) {
    int m = m0 + ty * 4 + r;
    int b = m >> 12, s = m & 4095;
    float4 o;
    o.x = acc[r][0]; o.y = acc[r][1]; o.z = acc[r][2]; o.w = acc[r][3];
    *reinterpret_cast<float4*>(outp + ((size_t)((b * HH + h) * SS + s)) * DD + tx * 4) = o;
  }
}

// ---------------------------------------------------------------------------
// Kernel 2: LSH hash, fp32; raw q / raw k. First-index argmax over [rv,-rv]
// (np.argmax tie-break; positive half wins ties).
// ---------------------------------------------------------------------------
__global__ __launch_bounds__(256) void k_hash(
    const float* __restrict__ qb, const float* __restrict__ kraw,
    const u32* __restrict__ rots, const int* __restrict__ flag,
    u8* __restrict__ bucketOut)
{
  const int bhn = blockIdx.x;       // 0..63 : (b*8+h)*4+n
  const int which = blockIdx.y;     // 0=q 1=k
  const int squarter = blockIdx.z;  // 0..3
  const int t = threadIdx.x;
  const int bh = bhn >> 2;
  const int h  = bh & 7;
  const int n  = bhn & 3;
  const int is32 = flag[0];

  __shared__ float rotS[64][65];    // [d][r]
  if (is32) {
    const float* rf = (const float*)rots;
    #pragma unroll
    for (int it = 0; it < 16; ++it) {
      int idx = t + it * 256;       // 4096 floats
      int d = idx >> 6, r = idx & 63;
      rotS[d][r] = rf[((size_t)((h * 64 + d) * 4 + n)) * 64 + r];
    }
  } else {
    #pragma unroll
    for (int it = 0; it < 8; ++it) {
      int idx = t + it * 256;       // 2048 u32 (4096 bf16)
      int d = idx >> 5, rp = idx & 31;
      u32 uv = rots[((size_t)((h * 64 + d) * 4 + n)) * 32 + rp];
      rotS[d][2 * rp]     = bflo(uv);
      rotS[d][2 * rp + 1] = bfhi(uv);
    }
  }
  __syncthreads();

  const float* src = ((which == 0) ? qb : kraw) + (size_t)bh * SS * DD;
  u8* bout = bucketOut + ((size_t)(which * 64 + bhn)) * SS;

  for (int ii = 0; ii < 4; ++ii) {
    int s = squarter * 1024 + ii * 256 + t;
    const float* row = src + (size_t)s * DD;
    float vec[64];
    #pragma unroll
    for (int d4 = 0; d4 < 16; ++d4) {
      float4 v4 = *reinterpret_cast<const float4*>(row + d4 * 4);
      vec[d4 * 4 + 0] = v4.x; vec[d4 * 4 + 1] = v4.y;
      vec[d4 * 4 + 2] = v4.z; vec[d4 * 4 + 3] = v4.w;
    }
    float bestP = -1e30f, bestN = -1e30f;
    int idxP = 0, idxN = 0;
    #pragma unroll 1
    for (int r0 = 0; r0 < 64; r0 += 16) {
      float acc[16];
      #pragma unroll
      for (int rr = 0; rr < 16; ++rr) acc[rr] = 0.0f;
      #pragma unroll
      for (int d = 0; d < 64; ++d) {
        float vd = vec[d];
        #pragma unroll
        for (int rr = 0; rr < 16; ++rr) acc[rr] += vd * rotS[d][r0 + rr];
      }
      #pragma unroll
      for (int rr = 0; rr < 16; ++rr) {
        float a = acc[rr];
        int r = r0 + rr;
        if (a > bestP) { bestP = a; idxP = r; }
        if (-a > bestN) { bestN = -a; idxN = r; }
      }
    }
    int bucket = (bestP >= bestN) ? idxP : (64 + idxN);
    bout[s] = (u8)bucket;
  }
}

// ---------------------------------------------------------------------------
// Kernel 3: stable counting sort per (b,h,round,which): 4096 items, 128 bins.
// ---------------------------------------------------------------------------
__global__ __launch_bounds__(256) void k_sort(
    const u8* __restrict__ bucketIn, int* __restrict__ sq_pos, int* __restrict__ sk_pos)
{
  const int bhn = blockIdx.x, which = blockIdx.y;
  const int t = threadIdx.x;
  const int bh = bhn >> 2, n = bhn & 3;
  __shared__ u8 bk[4096];
  __shared__ int cntS[128];
  __shared__ int startS[128];
  const u8* bin = bucketIn + ((size_t)(which * 64 + bhn)) * SS;
  #pragma unroll
  for (int it = 0; it < 4; ++it)
    ((u32*)bk)[t + it * 256] = ((const u32*)bin)[t + it * 256];
  __syncthreads();
  if (t < 128) {
    int c = 0;
    for (int s = 0; s < 4096; ++s) c += (bk[s] == (u8)t) ? 1 : 0;
    cntS[t] = c;
  }
  __syncthreads();
  if (t == 0) {
    int run = 0;
    for (int b2 = 0; b2 < 128; ++b2) { startS[b2] = run; run += cntS[b2]; }
  }
  __syncthreads();
  int* outp = ((which == 0) ? sq_pos : sk_pos) + (size_t)bh * RANKS + n * SS;
  if (t < 128) {
    int off = startS[t];
    for (int s = 0; s < 4096; ++s) {
      if (bk[s] == (u8)t) { outp[off++] = s; }
    }
  }
}

// ---------------------------------------------------------------------------
// Kernel 4a: attention phase A — logits only. One block per (b,h,chunk).
// K normalized in-LDS from kraw. Writes L scattered via sk (= undo_k).
// ---------------------------------------------------------------------------
__global__ __launch_bounds__(256) void k_attn_logits(
    const float* __restrict__ qb, const float* __restrict__ kraw,
    const int* __restrict__ sq_pos, const int* __restrict__ sk_pos,
    float* __restrict__ logit_uns)
{
  const int c = blockIdx.x;
  const int h = blockIdx.y, b = blockIdx.z;
  const int bh = b * HH + h;
  const int t = threadIdx.x;
  const int cprev = (c + NCC - 1) & (NCC - 1);

  __shared__ float Qs[64][68];
  __shared__ float KVs[128][68];
  __shared__ float sc[128];
  __shared__ int kposS[128], mposS[128];

  if (t < 128) {
    int slot = (t < 64) ? (cprev * 64 + t) : (c * 64 + (t - 64));
    kposS[t] = sk_pos[(size_t)bh * RANKS + slot];
    mposS[t] = sq_pos[(size_t)bh * RANKS + slot];
  }
  __syncthreads();

  const float* qbase = qb + (size_t)bh * SS * DD;
  const float* kbase = kraw + (size_t)bh * SS * DD;

  #pragma unroll
  for (int it = 0; it < 4; ++it) {
    int idx = t + it * 256;
    int i = idx >> 4, d4 = idx & 15;
    *reinterpret_cast<float4*>(&Qs[i][d4 * 4]) =
        *reinterpret_cast<const float4*>(qbase + (size_t)mposS[64 + i] * DD + d4 * 4);
  }
  #pragma unroll
  for (int it = 0; it < 8; ++it) {
    int idx = t + it * 256;
    int j = idx >> 4, d4 = idx & 15;
    *reinterpret_cast<float4*>(&KVs[j][d4 * 4]) =
        *reinterpret_cast<const float4*>(kbase + (size_t)kposS[j] * DD + d4 * 4);
  }
  __syncthreads();
  if (t < 128) {
    float ms = 0.f;
    #pragma unroll 8
    for (int d = 0; d < 64; ++d) { float x = KVs[t][d]; ms += x * x; }
    sc[t] = 0.125f / sqrtf(ms * (1.0f / 64.0f) + 1e-6f);
  }
  __syncthreads();
  #pragma unroll
  for (int it = 0; it < 8; ++it) {
    int idx = t + it * 256;
    int j = idx >> 4, d4 = idx & 15;
    float s_ = sc[j];
    float4 v4 = *reinterpret_cast<float4*>(&KVs[j][d4 * 4]);
    v4.x *= s_; v4.y *= s_; v4.z *= s_; v4.w *= s_;
    *reinterpret_cast<float4*>(&KVs[j][d4 * 4]) = v4;
  }
  __syncthreads();

  const int i = t >> 2, j0 = t & 3;
  const int myqpos = mposS[64 + i];

  float accD[32];
  #pragma unroll
  for (int jj = 0; jj < 32; ++jj) accD[jj] = 0.f;
  #pragma unroll 4
  for (int d0 = 0; d0 < 16; ++d0) {
    float4 q4 = *reinterpret_cast<const float4*>(&Qs[i][d0 * 4]);
    #pragma unroll
    for (int jj = 0; jj < 32; ++jj) {
      float4 k4 = *reinterpret_cast<const float4*>(&KVs[j0 + 4 * jj][d0 * 4]);
      accD[jj] += q4.x * k4.x + q4.y * k4.y + q4.z * k4.z + q4.w * k4.w;
    }
  }
  #pragma unroll
  for (int jj = 0; jj < 32; ++jj) {
    if (mposS[j0 + 4 * jj] == myqpos) accD[jj] = -100000.0f;
  }
  float m = -3.4e38f;
  #pragma unroll
  for (int jj = 0; jj < 32; ++jj) m = fmaxf(m, accD[jj]);
  m = fmaxf(m, __shfl_xor(m, 1));
  m = fmaxf(m, __shfl_xor(m, 2));
  float ssum = 0.f;
  #pragma unroll
  for (int jj = 0; jj < 32; ++jj) ssum += expf(accD[jj] - m);
  ssum += __shfl_xor(ssum, 1);
  ssum += __shfl_xor(ssum, 2);
  float L = m + logf(ssum);
  const int n = c >> 6;
  const int sdst = kposS[64 + i];
  if (j0 == 0) logit_uns[(size_t)(bh * NHH + n) * SS + sdst] = L;
}

// ---------------------------------------------------------------------------
// Kernel 4b: combine weights — softmax over the NH rounds' logits per position.
// ---------------------------------------------------------------------------
__global__ __launch_bounds__(256) void k_weights(
    const float* __restrict__ logit_uns, float* __restrict__ wcomb)
{
  int flat = blockIdx.x * 256 + threadIdx.x;  // 65536 = 16 * 4096
  int s = flat & 4095, bh = flat >> 12;
  size_t base = (size_t)bh * RANKS + s;
  float L0 = logit_uns[base];
  float L1 = logit_uns[base + SS];
  float L2 = logit_uns[base + 2 * SS];
  float L3 = logit_uns[base + 3 * SS];
  float m = fmaxf(fmaxf(L0, L1), fmaxf(L2, L3));
  float e0 = expf(L0 - m), e1 = expf(L1 - m), e2 = expf(L2 - m), e3 = expf(L3 - m);
  float inv = 1.0f / (e0 + e1 + e2 + e3);
  wcomb[base]          = e0 * inv;
  wcomb[base + SS]     = e1 * inv;
  wcomb[base + 2 * SS] = e2 * inv;
  wcomb[base + 3 * SS] = e3 * inv;
}

// ---------------------------------------------------------------------------
// Kernel 4c: attention phase B — full attention, weighted by wcomb, atomicAdd
// directly into fp32 d_out [B,S,H*D]. Each element gets exactly NH(=4) adds.
// ---------------------------------------------------------------------------
__global__ __launch_bounds__(256) void k_attn_pv(
    const float* __restrict__ qb, const float* __restrict__ kraw,
    const float* __restrict__ vb,
    const int* __restrict__ sq_pos, const int* __restrict__ sk_pos,
    const float* __restrict__ wcomb, float* __restrict__ outp)
{
  const int c = blockIdx.x;
  const int h = blockIdx.y, b = blockIdx.z;
  const int bh = b * HH + h;
  const int t = threadIdx.x;
  const int cprev = (c + NCC - 1) & (NCC - 1);

  __shared__ float Qs[64][68];
  __shared__ float KVs[128][68];
  __shared__ float sc[128];
  __shared__ int kposS[128], mposS[128];

  if (t < 128) {
    int slot = (t < 64) ? (cprev * 64 + t) : (c * 64 + (t - 64));
    kposS[t] = sk_pos[(size_t)bh * RANKS + slot];
    mposS[t] = sq_pos[(size_t)bh * RANKS + slot];
  }
  __syncthreads();

  const float* qbase = qb + (size_t)bh * SS * DD;
  const float* kbase = kraw + (size_t)bh * SS * DD;
  const float* vbase = vb + (size_t)bh * SS * DD;

  #pragma unroll
  for (int it = 0; it < 4; ++it) {
    int idx = t + it * 256;
    int i = idx >> 4, d4 = idx & 15;
    *reinterpret_cast<float4*>(&Qs[i][d4 * 4]) =
        *reinterpret_cast<const float4*>(qbase + (size_t)mposS[64 + i] * DD + d4 * 4);
  }
  #pragma unroll
  for (int it = 0; it < 8; ++it) {
    int idx = t + it * 256;
    int j = idx >> 4, d4 = idx & 15;
    *reinterpret_cast<float4*>(&KVs[j][d4 * 4]) =
        *reinterpret_cast<const float4*>(kbase + (size_t)kposS[j] * DD + d4 * 4);
  }
  __syncthreads();
  if (t < 128) {
    float ms = 0.f;
    #pragma unroll 8
    for (int d = 0; d < 64; ++d) { float x = KVs[t][d]; ms += x * x; }
    sc[t] = 0.125f / sqrtf(ms * (1.0f / 64.0f) + 1e-6f);
  }
  __syncthreads();
  #pragma unroll
  for (int it = 0; it < 8; ++it) {
    int idx = t + it * 256;
    int j = idx >> 4, d4 = idx & 15;
    float s_ = sc[j];
    float4 v4 = *reinterpret_cast<float4*>(&KVs[j][d4 * 4]);
    v4.x *= s_; v4.y *= s_; v4.z *= s_; v4.w *= s_;
    *reinterpret_cast<float4*>(&KVs[j][d4 * 4]) = v4;
  }
  __syncthreads();

  const int i = t >> 2, j0 = t & 3;
  const int myqpos = mposS[64 + i];

  float accD[32];
  #pragma unroll
  for (int jj = 0; jj < 32; ++jj) accD[jj] = 0.f;
  #pragma unroll 4
  for (int d0 = 0; d0 < 16; ++d0) {
    float4 q4 = *reinterpret_cast<const float4*>(&Qs[i][d0 * 4]);
    #pragma unroll
    for (int jj = 0; jj < 32; ++jj) {
      float4 k4 = *reinterpret_cast<const float4*>(&KVs[j0 + 4 * jj][d0 * 4]);
      accD[jj] += q4.x * k4.x + q4.y * k4.y + q4.z * k4.z + q4.w * k4.w;
    }
  }
  #pragma unroll
  for (int jj = 0; jj < 32; ++jj) {
    if (mposS[j0 + 4 * jj] == myqpos) accD[jj] = -100000.0f;
  }
  float m = -3.4e38f;
  #pragma unroll
  for (int jj = 0; jj < 32; ++jj) m = fmaxf(m, accD[jj]);
  m = fmaxf(m, __shfl_xor(m, 1));
  m = fmaxf(m, __shfl_xor(m, 2));
  float ssum = 0.f;
  #pragma unroll
  for (int jj = 0; jj < 32; ++jj) { float e = expf(accD[jj] - m); accD[jj] = e; ssum += e; }
  ssum += __shfl_xor(ssum, 1);
  ssum += __shfl_xor(ssum, 2);
  float inv = 1.0f / ssum;
  #pragma unroll
  for (int jj = 0; jj < 32; ++jj) accD[jj] *= inv;

  __syncthreads();  // done with K in LDS; reload V
  #pragma unroll
  for (int it = 0; it < 8; ++it) {
    int idx = t + it * 256;
    int j = idx >> 4, d4 = idx & 15;
    *reinterpret_cast<float4*>(&KVs[j][d4 * 4]) =
        *reinterpret_cast<const float4*>(vbase + (size_t)kposS[j] * DD + d4 * 4);
  }
  __syncthreads();

  float4 acc4[16];
  #pragma unroll
  for (int d4 = 0; d4 < 16; ++d4) acc4[d4] = make_float4(0.f, 0.f, 0.f, 0.f);
  #pragma unroll 4
  for (int jj = 0; jj < 32; ++jj) {
    float p = accD[jj];
    const int j = j0 + 4 * jj;
    #pragma unroll
    for (int d4 = 0; d4 < 16; ++d4) {
      float4 v4 = *reinterpret_cast<const float4*>(&KVs[j][d4 * 4]);
      acc4[d4].x += p * v4.x; acc4[d4].y += p * v4.y;
      acc4[d4].z += p * v4.z; acc4[d4].w += p * v4.w;
    }
  }
  #pragma unroll
  for (int d4 = 0; d4 < 16; ++d4) {
    acc4[d4].x += __shfl_xor(acc4[d4].x, 1); acc4[d4].x += __shfl_xor(acc4[d4].x, 2);
    acc4[d4].y += __shfl_xor(acc4[d4].y, 1); acc4[d4].y += __shfl_xor(acc4[d4].y, 2);
    acc4[d4].z += __shfl_xor(acc4[d4].z, 1); acc4[d4].z += __shfl_xor(acc4[d4].z, 2);
    acc4[d4].w += __shfl_xor(acc4[d4].w, 1); acc4[d4].w += __shfl_xor(acc4[d4].w, 2);
  }
  const int n = c >> 6;
  const int sdst = kposS[64 + i];
  const float w = wcomb[(size_t)(bh * NHH + n) * SS + sdst];
  // fp32 output, [B,S,H*D]
  float* orow = outp + ((size_t)(b * SS + sdst)) * (HH * DD) + h * DD;
  #pragma unroll
  for (int dd = 0; dd < 4; ++dd) {
    float4 a = acc4[j0 * 4 + dd];
    int d = j0 * 16 + dd * 4;
    atomicAdd(&orow[d + 0], w * a.x);
    atomicAdd(&orow[d + 1], w * a.y);
    atomicAdd(&orow[d + 2], w * a.z);
    atomicAdd(&orow[d + 3], w * a.w);
  }
}

// ---------------------------------------------------------------------------
// Kernel Z: zero the fp32 output (harness poisons it before timed launches).
// ---------------------------------------------------------------------------
__global__ __launch_bounds__(256) void k_zero_out(float* __restrict__ outp)
{
  int flat = blockIdx.x * 256 + threadIdx.x;  // grid 4096 -> 1,048,576 float4
  float4 z = make_float4(0.f, 0.f, 0.f, 0.f);
  *reinterpret_cast<float4*>(outp + (size_t)flat * 4) = z;
}

// ---------------------------------------------------------------------------
extern "C" void kernel_launch(void* const* d_in, const int* in_sizes, int n_in,
                              void* d_out, int out_size, void* d_ws, size_t ws_size,
                              hipStream_t stream)
{
  (void)in_sizes; (void)n_in; (void)out_size; (void)ws_size;
  const u32* dec = (const u32*)d_in[0];
  const u32* hid = (const u32*)d_in[1];
  const u32* wqk = (const u32*)d_in[2];
  const u32* wv  = (const u32*)d_in[3];
  const u32* rot = (const u32*)d_in[4];

  const size_t QKV  = (size_t)BB * HH * SS * DD;   // 4,194,304 elems
  const size_t LOGU = (size_t)BB * HH * NHH * SS;  // 262,144

  // Workspace layout, ~55 MB total:
  float* qb       = (float*)d_ws;                   // 16.78 MB
  float* kraw     = qb + QKV;                       // 16.78 MB
  float* vb       = kraw + QKV;                     // 16.78 MB
  float* logit    = vb + QKV;                       // 1.05 MB
  float* wcomb    = logit + LOGU;                   // 1.05 MB
  int*   sq_pos   = (int*)(wcomb + LOGU);           // 1.05 MB
  int*   sk_pos   = sq_pos + LOGU;                  // 1.05 MB
  u8*    buckets  = (u8*)(sk_pos + LOGU);           // 0.52 MB
  int*   flag     = (int*)(buckets + 2 * 64 * SS);  // 4 B

  hipMemsetAsync(flag, 0, sizeof(int), stream);
  k_zero_out<<<dim3(4096), 256, 0, stream>>>((float*)d_out);
  k_detect<<<dim3(512), 256, 0, stream>>>(wqk, flag);
  k_proj<<<dim3(128, 8, 3), 256, 0, stream>>>(dec, hid, wqk, wv, flag, qb, kraw, vb);
  k_hash<<<dim3(64, 2, 4), 256, 0, stream>>>(qb, kraw, rot, flag, buckets);
  k_sort<<<dim3(64, 2), 256, 0, stream>>>(buckets, sq_pos, sk_pos);
  k_attn_logits<<<dim3(NCC, HH, BB), 256, 0, stream>>>(qb, kraw, sq_pos, sk_pos, logit);
  k_weights<<<dim3(256), 256, 0, stream>>>(logit, wcomb);
  k_attn_pv<<<dim3(NCC, HH, BB), 256, 0, stream>>>(qb, kraw, vb, sq_pos, sk_pos, wcomb, (float*)d_out);
}